// Round 4
// baseline (12935.451 us; speedup 1.0000x reference)
//
#include <hip/hip_runtime.h>
#include <hip/hip_bf16.h>

// Problem dims (fixed by reference): N=256, T=32, F=H=512, L=2
#define HD 512
#define TT 32
#define NB 256
#define SEQROWS 8193          // 1 zero row + up to 8192 chain steps
#define GA 64                 // workgroups per role (A=layer0, B=layer1)
#define RPW 8                 // h rows owned per WG (GA*RPW = HD)
#define SENT_U 0x7FC0ABCDu    // quiet-NaN sentinel: unreachable by GRU math

__device__ __forceinline__ float fast_sigmoid(float x) {
    return 1.0f / (1.0f + __expf(-x));
}
__device__ __forceinline__ float fast_tanh(float x) {
    return 1.0f - 2.0f / (__expf(2.0f * x) + 1.0f);
}
// Opaque pin: forces v into a VGPR and forbids rematerializing its producer
// load inside the loop (R2/R3: LLVM sank the 96 weight loads into the step
// loop -> ~1.3us/step of re-fetch; VGPR_Count 88/80 < weight count proved it)
__device__ __forceinline__ void pin(float& v) { asm volatile("" : "+v"(v)); }

__device__ __forceinline__ float coh_load(const float* p) {
    return __hip_atomic_load(p, __ATOMIC_RELAXED, __HIP_MEMORY_SCOPE_AGENT);
}
__device__ __forceinline__ void coh_store(float* p, float v) {
    __hip_atomic_store(p, v, __ATOMIC_RELAXED, __HIP_MEMORY_SCOPE_AGENT);
}

// ---------------------------------------------------------------------------
// init: block 0 -> dates scan, active list, jmap, S, zero h row 0, out dates;
//       blocks 1..1024 -> sentinel-fill rows 1..8192 of both h sequences.
// ---------------------------------------------------------------------------
__global__ __launch_bounds__(256) void init_kernel(
    const int* __restrict__ dates, float* __restrict__ out,
    float* __restrict__ h0seq, float* __restrict__ h1seq,
    int* __restrict__ act_idx, int* __restrict__ jmap, int* __restrict__ S_ptr)
{
    const int b = blockIdx.x, tid = threadIdx.x;
    if (b == 0) {
        __shared__ int sc[NB];
        int d = dates[tid];
        int active = (tid == 0) ? 1 : (d != dates[tid - 1] ? 1 : 0);
        sc[tid] = active;
        for (int off = 1; off < NB; off <<= 1) {
            __syncthreads();
            int v = sc[tid] + ((tid >= off) ? sc[tid - off] : 0);
            __syncthreads();
            sc[tid] = v;
        }
        __syncthreads();
        int incl = sc[tid];               // inclusive actives in [0..tid]
        jmap[tid] = incl - 1;
        if (active) act_idx[incl - 1] = tid;
        if (tid == NB - 1) *S_ptr = incl * TT;
        out[tid] = (float)d;              // output 0: dates passthrough
        for (int i = tid; i < HD; i += 256) { h0seq[i] = 0.f; h1seq[i] = 0.f; }
    } else {
        const uint4 sv = make_uint4(SENT_U, SENT_U, SENT_U, SENT_U);
        const size_t HALF = (size_t)(SEQROWS - 1) * HD / 4;   // uint4 per buffer
        size_t base = (size_t)(b - 1) * 2048 + tid;
#pragma unroll
        for (int k = 0; k < 8; k++) {
            size_t i = base + (size_t)k * 256;                // uint4 index
            uint4* dst = (i < HALF)
                ? reinterpret_cast<uint4*>(h0seq + HD) + i
                : reinterpret_cast<uint4*>(h1seq + HD) + (i - HALF);
            *dst = sv;
        }
    }
}

// ---------------------------------------------------------------------------
// chain: 128 persistent WGs, sentinel-poll handoff (no flags, no fences).
// WGs 0..63 = layer0 (input x), WGs 64..127 = layer1 (input = h0 stream).
// Thread (hl=tid>>6, c=tid&63) owns h row hi=g*8+hl, columns {c+64j} j=0..7.
// 48 weights/thread, asm-pinned into VGPRs.
// ---------------------------------------------------------------------------
__global__ __launch_bounds__(512, 2) void chain_kernel(
    const float* __restrict__ x,
    const float* __restrict__ Wih0, const float* __restrict__ Whh0,
    const float* __restrict__ bih0, const float* __restrict__ bhh0,
    const float* __restrict__ Wih1, const float* __restrict__ Whh1,
    const float* __restrict__ bih1, const float* __restrict__ bhh1,
    float* h0seq, float* h1seq,
    const int* __restrict__ act_idx, const int* __restrict__ S_ptr)
{
    const int wg   = blockIdx.x;
    const bool roleB = (wg >= GA);
    const int g    = roleB ? wg - GA : wg;     // 0..63
    const int tid  = threadIdx.x;
    const int hl   = tid >> 6;                 // 0..7: local h row
    const int c    = tid & 63;                 // 0..63: column lane
    const int hi   = g * RPW + hl;             // owned h output index

    __shared__ float hbufs[2][HD];             // own h(s-1) row, double-buffered
    __shared__ float xbufs[2][HD];             // role B: h0(s) row

    const float* Wi = roleB ? Wih1 : Wih0;
    const float* Wh = roleB ? Whh1 : Whh0;
    const float* bi = roleB ? bih1 : bih0;
    const float* bh = roleB ? bhh1 : bhh0;

    // ---- 48 register-resident weights (columns c + 64j), asm-pinned ----
    float wir[RPW], wiz[RPW], win[RPW], whr[RPW], whz[RPW], whn[RPW];
    {
        const size_t GS = (size_t)HD * HD;
        const float* rI = Wi + (size_t)hi * HD + c;
        const float* rH = Wh + (size_t)hi * HD + c;
#pragma unroll
        for (int j = 0; j < RPW; j++) {
            wir[j] = rI[64 * j];            pin(wir[j]);
            wiz[j] = rI[GS + 64 * j];       pin(wiz[j]);
            win[j] = rI[2 * GS + 64 * j];   pin(win[j]);
            whr[j] = rH[64 * j];            pin(whr[j]);
            whz[j] = rH[GS + 64 * j];       pin(whz[j]);
            whn[j] = rH[2 * GS + 64 * j];   pin(whn[j]);
        }
    }
    const float br   = bi[hi] + bh[hi];
    const float bz   = bi[HD + hi] + bh[HD + hi];
    const float bin_ = bi[2 * HD + hi];
    const float bhn_ = bh[2 * HD + hi];

    const int S = *S_ptr;
    float* outseq = roleB ? h1seq : h0seq;
    float hown = 0.0f;                         // leader lanes carry their h

    for (int s = 0; s < S; s++) {
        const int buf = s & 1;

        // ---- role A: x slice + x-partials BEFORE the wait (independent) ----
        float pr = 0.f, pz = 0.f, pin_ = 0.f;
        if (!roleB) {
            int n = act_idx[s >> 5];
            const float* xp = x + ((size_t)n * TT + (s & 31)) * HD + c;
            float xr[RPW];
#pragma unroll
            for (int j = 0; j < RPW; j++) xr[j] = xp[64 * j];
#pragma unroll
            for (int j = 0; j < RPW; j++) {
                pr   = fmaf(wir[j], xr[j], pr);
                pz   = fmaf(wiz[j], xr[j], pz);
                pin_ = fmaf(win[j], xr[j], pin_);
            }
        }

        // ---- sentinel-poll the input rows: 1 coalesced word per thread ----
        const float* hp = outseq + (size_t)s * HD + tid;
        float hv = coh_load(hp);
        if (!roleB) {
            int it = 0;
            while (__float_as_uint(hv) == SENT_U) {
                hv = coh_load(hp);
                if (++it > 20000000) break;    // fail loudly, don't hang
            }
            hbufs[buf][tid] = hv;
        } else {
            const float* xp2 = h0seq + (size_t)(s + 1) * HD + tid;
            float xv = coh_load(xp2);
            int it = 0;
            while (__float_as_uint(hv) == SENT_U || __float_as_uint(xv) == SENT_U) {
                if (__float_as_uint(hv) == SENT_U) hv = coh_load(hp);
                if (__float_as_uint(xv) == SENT_U) xv = coh_load(xp2);
                if (++it > 20000000) break;
            }
            hbufs[buf][tid] = hv;
            xbufs[buf][tid] = xv;
        }
        __syncthreads();   // only barrier per step (double-buffered LDS)

        // ---- post-detect matvec ----
        float phn = 0.f;
#pragma unroll
        for (int j = 0; j < RPW; j++) {
            float h2 = hbufs[buf][c + 64 * j];
            pr  = fmaf(whr[j], h2, pr);
            pz  = fmaf(whz[j], h2, pz);
            phn = fmaf(whn[j], h2, phn);
        }
        if (roleB) {
#pragma unroll
            for (int j = 0; j < RPW; j++) {
                float x2 = xbufs[buf][c + 64 * j];
                pr   = fmaf(wir[j], x2, pr);
                pz   = fmaf(wiz[j], x2, pz);
                pin_ = fmaf(win[j], x2, pin_);
            }
        }
#pragma unroll
        for (int m = 1; m < 64; m <<= 1) {
            pr   += __shfl_xor(pr,   m, 64);
            pz   += __shfl_xor(pz,   m, 64);
            pin_ += __shfl_xor(pin_, m, 64);
            phn  += __shfl_xor(phn,  m, 64);
        }
        if (c == 0) {
            float r  = fast_sigmoid(pr + br);
            float z  = fast_sigmoid(pz + bz);
            float nn = fast_tanh(pin_ + bin_ + r * (phn + bhn_));
            hown = (1.0f - z) * nn + z * hown;
            coh_store(outseq + (size_t)(s + 1) * HD + hi, hown);
        }
    }
}

// ---------------------------------------------------------------------------
// finalize: states[n] = h1 after last step of active element jmap[n].
// ---------------------------------------------------------------------------
__global__ __launch_bounds__(256) void finalize_kernel(
    const float* __restrict__ h1seq, const int* __restrict__ jmap,
    float* __restrict__ out)
{
    const int n = blockIdx.x;
    const int j = jmap[n];
    const float* src = h1seq + ((size_t)j * TT + TT) * HD;   // row (j+1)*32
    float* dst = out + NB + (size_t)n * HD;
    for (int i = threadIdx.x; i < HD; i += 256)
        dst[i] = coh_load(src + i);
}

extern "C" void kernel_launch(void* const* d_in, const int* in_sizes, int n_in,
                              void* d_out, int out_size, void* d_ws, size_t ws_size,
                              hipStream_t stream)
{
    const int*   dates = (const int*)d_in[0];
    const float* x     = (const float*)d_in[1];
    const float* Wih0  = (const float*)d_in[2];
    const float* Whh0  = (const float*)d_in[3];
    const float* bih0  = (const float*)d_in[4];
    const float* bhh0  = (const float*)d_in[5];
    const float* Wih1  = (const float*)d_in[6];
    const float* Whh1  = (const float*)d_in[7];
    const float* bih1  = (const float*)d_in[8];
    const float* bhh1  = (const float*)d_in[9];
    float* out = (float*)d_out;

    // workspace layout (~33.6 MB)
    float* h0seq  = (float*)d_ws;                       // 8193*512
    float* h1seq  = h0seq + (size_t)SEQROWS * HD;       // 8193*512
    int*   act_i  = (int*)(h1seq + (size_t)SEQROWS * HD);
    int*   jmap   = act_i + NB;                         // 256
    int*   S_ptr  = jmap + NB;                          // 1

    hipLaunchKernelGGL(init_kernel, dim3(1025), dim3(256), 0, stream,
                       dates, out, h0seq, h1seq, act_i, jmap, S_ptr);
    hipLaunchKernelGGL(chain_kernel, dim3(2 * GA), dim3(512), 0, stream,
                       x, Wih0, Whh0, bih0, bhh0, Wih1, Whh1, bih1, bhh1,
                       h0seq, h1seq, act_i, S_ptr);
    hipLaunchKernelGGL(finalize_kernel, dim3(NB), dim3(256), 0, stream,
                       h1seq, jmap, out);
}

// Round 5
// 7978.384 us; speedup vs baseline: 1.6213x; 1.6213x over previous
//
#include <hip/hip_runtime.h>
#include <hip/hip_bf16.h>

// Problem dims (fixed by reference): N=256, T=32, F=H=512, L=2
#define HD 512
#define TT 32
#define NB 256
#define SEQROWS 8193          // 1 zero row + up to 8192 chain steps
#define GA 32                 // workgroups per role (A=layer0, B=layer1)
#define SENT_U 0x7FC0ABCDu    // quiet-NaN sentinel: unreachable by GRU math
#define TAU 90ull             // schedule period in 10ns ticks (900ns @100MHz)
#define T0_MARGIN 300ull      // 3us margin between rendezvous and step 0

__device__ __forceinline__ float fast_sigmoid(float x) {
    return 1.0f / (1.0f + __expf(-x));
}
__device__ __forceinline__ float fast_tanh(float x) {
    return 1.0f - 2.0f / (__expf(2.0f * x) + 1.0f);
}
__device__ __forceinline__ void pinv(float& v) { asm volatile("" : "+v"(v)); }

__device__ __forceinline__ float llc_load(const float* p) {
    return __hip_atomic_load(p, __ATOMIC_RELAXED, __HIP_MEMORY_SCOPE_AGENT);
}
__device__ __forceinline__ void llc_store(float* p, float v) {
    __hip_atomic_store(p, v, __ATOMIC_RELAXED, __HIP_MEMORY_SCOPE_AGENT);
}

// ---------------------------------------------------------------------------
// init: block 0 -> dates scan, active list, jmap, S, zero h row 0, rendezvous
//       slots, out dates; blocks 1..1024 -> sentinel-fill rows 1..8192.
// ---------------------------------------------------------------------------
__global__ __launch_bounds__(256) void init_kernel(
    const int* __restrict__ dates, float* __restrict__ out,
    float* __restrict__ h0seq, float* __restrict__ h1seq,
    int* __restrict__ act_idx, int* __restrict__ jmap, int* __restrict__ S_ptr,
    int* __restrict__ arrive, unsigned long long* __restrict__ t0_slot)
{
    const int b = blockIdx.x, tid = threadIdx.x;
    if (b == 0) {
        __shared__ int sc[NB];
        int d = dates[tid];
        int active = (tid == 0) ? 1 : (d != dates[tid - 1] ? 1 : 0);
        sc[tid] = active;
        for (int off = 1; off < NB; off <<= 1) {
            __syncthreads();
            int v = sc[tid] + ((tid >= off) ? sc[tid - off] : 0);
            __syncthreads();
            sc[tid] = v;
        }
        __syncthreads();
        int incl = sc[tid];               // inclusive actives in [0..tid]
        jmap[tid] = incl - 1;
        if (active) act_idx[incl - 1] = tid;
        if (tid == NB - 1) *S_ptr = incl * TT;
        if (tid == 0) { *arrive = 0; *t0_slot = 0ull; }
        out[tid] = (float)d;              // output 0: dates passthrough
        for (int i = tid; i < HD; i += 256) { h0seq[i] = 0.f; h1seq[i] = 0.f; }
    } else {
        const uint4 sv = make_uint4(SENT_U, SENT_U, SENT_U, SENT_U);
        const size_t HALF = (size_t)(SEQROWS - 1) * HD / 4;   // uint4 per buffer
        size_t base = (size_t)(b - 1) * 2048 + tid;
#pragma unroll
        for (int k = 0; k < 8; k++) {
            size_t i = base + (size_t)k * 256;                // uint4 index
            uint4* dst = (i < HALF)
                ? reinterpret_cast<uint4*>(h0seq + HD) + i
                : reinterpret_cast<uint4*>(h1seq + HD) + (i - HALF);
            *dst = sv;
        }
    }
}

// ---------------------------------------------------------------------------
// chain: 64 persistent WGs, clock-scheduled pipeline (s_memrealtime-gated,
// sentinel fallback). WGs 0..31 = layer0 (input x), 32..63 = layer1.
// Thread (hl=tid>>5, c=tid&31) owns row hi=g*16+hl, cols {c+32j} j=0..15.
// Publication: 16 leader values gathered in LDS, stored by lanes 0..15 of
// wave 0 as ONE 64B coalesced LLC transaction (line flips atomically).
// Schedule: T0 published by last rendezvous arriver (same VALUE for all WGs
// => zero schedule skew); role A step s gated at T0+s*TAU, role B at +1 slot.
// ---------------------------------------------------------------------------
__global__ __launch_bounds__(512, 2) void chain_kernel(
    const float* __restrict__ x,
    const float* __restrict__ Wih0, const float* __restrict__ Whh0,
    const float* __restrict__ bih0, const float* __restrict__ bhh0,
    const float* __restrict__ Wih1, const float* __restrict__ Whh1,
    const float* __restrict__ bih1, const float* __restrict__ bhh1,
    float* h0seq, float* h1seq,
    const int* __restrict__ act_idx, const int* __restrict__ S_ptr,
    int* arrive, unsigned long long* t0_slot)
{
    const int wg   = blockIdx.x;
    const bool roleB = (wg >= GA);
    const int g    = roleB ? wg - GA : wg;     // 0..31
    const int tid  = threadIdx.x;
    const int hl   = tid >> 5;                 // 0..15: local h row
    const int c    = tid & 31;                 // 0..31: column lane
    const int hi   = g * 16 + hl;              // owned h output index

    __shared__ float hbuf[HD];                 // own-role h(s-1) row
    __shared__ float xbuf[HD];                 // role B: h0(s) row
    __shared__ float gbuf[16];                 // publication gather

    const float* Wi = roleB ? Wih1 : Wih0;
    const float* Wh = roleB ? Whh1 : Whh0;
    const float* bi = roleB ? bih1 : bih0;
    const float* bh = roleB ? bhh1 : bhh0;

    // ---- 96 weights/thread (pinned; allocator may AGPR-home them: fine) ----
    float wir[16], wiz[16], win[16], whr[16], whz[16], whn[16];
    {
        const size_t GS = (size_t)HD * HD;
        const float* rI = Wi + (size_t)hi * HD + c;
        const float* rH = Wh + (size_t)hi * HD + c;
#pragma unroll
        for (int j = 0; j < 16; j++) {
            wir[j] = rI[32 * j];            pinv(wir[j]);
            wiz[j] = rI[GS + 32 * j];       pinv(wiz[j]);
            win[j] = rI[2 * GS + 32 * j];   pinv(win[j]);
            whr[j] = rH[32 * j];            pinv(whr[j]);
            whz[j] = rH[GS + 32 * j];       pinv(whz[j]);
            whn[j] = rH[2 * GS + 32 * j];   pinv(whn[j]);
        }
    }
    const float br   = bi[hi] + bh[hi];
    const float bz   = bi[HD + hi] + bh[HD + hi];
    const float bin_ = bi[2 * HD + hi];
    const float bhn_ = bh[2 * HD + hi];
    const int S = *S_ptr;

    // ---- rendezvous: weights loaded; last arriver publishes T0 value ----
    if (tid == 0) {
        int t = __hip_atomic_fetch_add(arrive, 1, __ATOMIC_RELAXED,
                                       __HIP_MEMORY_SCOPE_AGENT);
        if (t == 2 * GA - 1) {
            unsigned long long t0 = __builtin_amdgcn_s_memrealtime() + T0_MARGIN;
            __hip_atomic_store(t0_slot, t0, __ATOMIC_RELAXED,
                               __HIP_MEMORY_SCOPE_AGENT);
        }
    }
    // all threads poll the T0 value (same number everywhere -> zero skew)
    unsigned long long T0 = 0;
    {
        int it = 0;
        while ((T0 = __hip_atomic_load(t0_slot, __ATOMIC_RELAXED,
                                       __HIP_MEMORY_SCOPE_AGENT)) == 0ull) {
            __builtin_amdgcn_s_sleep(1);
            if (++it > 50000000) break;
        }
    }

    float* outseq = roleB ? h1seq : h0seq;
    float hown = 0.0f;
    unsigned long long gate = T0 + (roleB ? TAU : 0ull);

    for (int s = 0; s < S; s++, gate += TAU) {
        // ---- role A: x slice + x-partials BEFORE the gate (overlapped) ----
        float pr = 0.f, pz = 0.f, pin_ = 0.f;
        if (!roleB) {
            int n = act_idx[s >> 5];
            const float* xp = x + ((size_t)n * TT + (s & 31)) * HD + c;
            float xr[16];
#pragma unroll
            for (int j = 0; j < 16; j++) xr[j] = xp[32 * j];
#pragma unroll
            for (int j = 0; j < 16; j++) {
                pr   = fmaf(wir[j], xr[j], pr);
                pz   = fmaf(wiz[j], xr[j], pz);
                pin_ = fmaf(win[j], xr[j], pin_);
            }
        }

        // ---- wait for the schedule gate (SALU only, zero memory traffic) ----
        while ((long long)(__builtin_amdgcn_s_memrealtime() - gate) < 0) {}

        // ---- load input rows once; sentinel fallback if producer late ----
        const float* hp = outseq + (size_t)s * HD + tid;
        float hv = llc_load(hp);
        if (!roleB) {
            int it = 0;
            while (__float_as_uint(hv) == SENT_U) {
                __builtin_amdgcn_s_sleep(1);
                hv = llc_load(hp);
                if (++it > 20000000) break;
            }
            hbuf[tid] = hv;
        } else {
            const float* xp2 = h0seq + (size_t)(s + 1) * HD + tid;
            float xv = llc_load(xp2);
            int it = 0;
            while (__float_as_uint(hv) == SENT_U || __float_as_uint(xv) == SENT_U) {
                __builtin_amdgcn_s_sleep(1);
                if (__float_as_uint(hv) == SENT_U) hv = llc_load(hp);
                if (__float_as_uint(xv) == SENT_U) xv = llc_load(xp2);
                if (++it > 20000000) break;
            }
            hbuf[tid] = hv;
            xbuf[tid] = xv;
        }
        __syncthreads();

        // ---- matvec partials ----
        float phn = 0.f;
#pragma unroll
        for (int j = 0; j < 16; j++) {
            float h2 = hbuf[c + 32 * j];
            pr  = fmaf(whr[j], h2, pr);
            pz  = fmaf(whz[j], h2, pz);
            phn = fmaf(whn[j], h2, phn);
        }
        if (roleB) {
#pragma unroll
            for (int j = 0; j < 16; j++) {
                float x2 = xbuf[c + 32 * j];
                pr   = fmaf(wir[j], x2, pr);
                pz   = fmaf(wiz[j], x2, pz);
                pin_ = fmaf(win[j], x2, pin_);
            }
        }
#pragma unroll
        for (int m = 1; m < 32; m <<= 1) {
            pr   += __shfl_xor(pr,   m, 64);
            pz   += __shfl_xor(pz,   m, 64);
            pin_ += __shfl_xor(pin_, m, 64);
            phn  += __shfl_xor(phn,  m, 64);
        }
        if (c == 0) {
            float r  = fast_sigmoid(pr + br);
            float z  = fast_sigmoid(pz + bz);
            float nn = fast_tanh(pin_ + bin_ + r * (phn + bhn_));
            hown = (1.0f - z) * nn + z * hown;
            gbuf[hl] = hown;                   // gather for single-line publish
        }
        __syncthreads();
        // ---- publish: lanes 0..15 of wave 0 -> ONE 64B LLC transaction ----
        if (tid < 16)
            llc_store(outseq + (size_t)(s + 1) * HD + g * 16 + tid, gbuf[tid]);
    }
}

// ---------------------------------------------------------------------------
// finalize: states[n] = h1 after last step of active element jmap[n].
// ---------------------------------------------------------------------------
__global__ __launch_bounds__(256) void finalize_kernel(
    const float* __restrict__ h1seq, const int* __restrict__ jmap,
    float* __restrict__ out)
{
    const int n = blockIdx.x;
    const int j = jmap[n];
    const float* src = h1seq + ((size_t)j * TT + TT) * HD;   // row (j+1)*32
    float* dst = out + NB + (size_t)n * HD;
    for (int i = threadIdx.x; i < HD; i += 256)
        dst[i] = llc_load(src + i);
}

extern "C" void kernel_launch(void* const* d_in, const int* in_sizes, int n_in,
                              void* d_out, int out_size, void* d_ws, size_t ws_size,
                              hipStream_t stream)
{
    const int*   dates = (const int*)d_in[0];
    const float* x     = (const float*)d_in[1];
    const float* Wih0  = (const float*)d_in[2];
    const float* Whh0  = (const float*)d_in[3];
    const float* bih0  = (const float*)d_in[4];
    const float* bhh0  = (const float*)d_in[5];
    const float* Wih1  = (const float*)d_in[6];
    const float* Whh1  = (const float*)d_in[7];
    const float* bih1  = (const float*)d_in[8];
    const float* bhh1  = (const float*)d_in[9];
    float* out = (float*)d_out;

    // workspace layout (~33.6 MB)
    float* h0seq  = (float*)d_ws;                       // 8193*512
    float* h1seq  = h0seq + (size_t)SEQROWS * HD;       // 8193*512
    int*   act_i  = (int*)(h1seq + (size_t)SEQROWS * HD);
    int*   jmap   = act_i + NB;                         // 256
    int*   S_ptr  = jmap + NB;                          // 1
    int*   arrive = S_ptr + 1;                          // 1
    unsigned long long* t0_slot =
        (unsigned long long*)(arrive + 3);              // 8B-aligned

    hipLaunchKernelGGL(init_kernel, dim3(1025), dim3(256), 0, stream,
                       dates, out, h0seq, h1seq, act_i, jmap, S_ptr,
                       arrive, t0_slot);
    hipLaunchKernelGGL(chain_kernel, dim3(2 * GA), dim3(512), 0, stream,
                       x, Wih0, Whh0, bih0, bhh0, Wih1, Whh1, bih1, bhh1,
                       h0seq, h1seq, act_i, S_ptr, arrive, t0_slot);
    hipLaunchKernelGGL(finalize_kernel, dim3(NB), dim3(256), 0, stream,
                       h1seq, jmap, out);
}